// Round 13
// baseline (241.857 us; speedup 1.0000x reference)
//
#include <hip/hip_runtime.h>
#include <hip/hip_bf16.h>

#define F 1024
#define B_ROWS 16384

typedef short v8s __attribute__((ext_vector_type(8)));
typedef float v4f __attribute__((ext_vector_type(4)));
typedef unsigned short v8u __attribute__((ext_vector_type(8)));
typedef unsigned short ushort_t;

__device__ __forceinline__ unsigned short f2bf(float f) {
    unsigned int u = __builtin_bit_cast(unsigned int, f);
    u = (u + 0x7FFFu + ((u >> 16) & 1u)) >> 16;  // RNE
    return (unsigned short)u;
}

// Pack one A-fragment (8 fp32 bit-patterns -> 8 bf16, round-half-up) using
// ONLY shift/and/or -- no v_perm (r10/r12's perm-based pack is the prime
// suspect for their identical deterministic absmax failures; selector
// conventions are unverifiable from our ISA doc). Element e of the result
// = bf16 of input element e (low16 of word k = elem 2k, high16 = elem 2k+1).
__device__ __forceinline__ v8s pack_frag(uint4 lo, uint4 hi) {
    uint4 o;
    o.x = ((lo.y + 0x8000u) & 0xFFFF0000u) | ((lo.x + 0x8000u) >> 16);
    o.y = ((lo.w + 0x8000u) & 0xFFFF0000u) | ((lo.z + 0x8000u) >> 16);
    o.z = ((hi.y + 0x8000u) & 0xFFFF0000u) | ((hi.x + 0x8000u) >> 16);
    o.w = ((hi.w + 0x8000u) & 0xFFFF0000u) | ((hi.z + 0x8000u) >> 16);
    return __builtin_bit_cast(v8s, o);
}

// async global->LDS, 16B per lane. LDS dest = wave-uniform base + lane*16.
__device__ __forceinline__ void gload_lds16(const ushort_t* g, ushort_t* l) {
    __builtin_amdgcn_global_load_lds(
        (const __attribute__((address_space(1))) unsigned int*)g,
        (__attribute__((address_space(3))) unsigned int*)l,
        16, 0, 0);
}

// Fragment-packed B layout: chunk (grp, kg) = 16-row x 32-col bf16 block,
// lane l -> row grp*16 + (l&15), cols kg*32 + (l>>4)*8 .. +8. 1 KB/chunk.

// prep: [0,64) zero rowacc; [64,576) pack B = 0.5*(W+W^T).
// No X pass (conversion folded into gemm A-path).
__global__ __launch_bounds__(256) void prep_kernel(
        const float* __restrict__ w,
        ushort_t* __restrict__ Bp, float* __restrict__ acc) {
    const int bid  = blockIdx.x;
    const int tid  = threadIdx.x;
    const int lane = tid & 63;
    const int wave = tid >> 6;
    const int l16  = lane & 15;
    const int quad = lane >> 4;

    if (bid < 64) {
        acc[bid * 256 + tid] = 0.0f;
    } else {
        const int c  = (bid - 64) * 4 + wave;   // 0..2047
        const int i  = (c >> 5) * 16 + l16;     // A row
        const int j0 = (c & 31) * 32 + quad * 8;
        v8u o;
#pragma unroll
        for (int e = 0; e < 8; ++e) {
            const int j = j0 + e;
            float v = 0.0f;
            if (i != j) {
                const int a = min(i, j), b = max(i, j);
                const int k = a * (F - 1) - (a * (a - 1)) / 2 + (b - a - 1);
                v = 0.5f * w[k];  // scattered half is L2-resident (w = 2MB)
            }
            o[e] = f2bf(v);
        }
        *(v8u*)(Bp + (size_t)c * 512 + lane * 8) = o;
    }
}

// Hybrid GEMM (r9 structure, proven passing at 69 µs) + fused conversion:
//  - B fragments multicast through LDS, 16KB double-buffered chunks,
//    staged one chunk ahead of the barrier (7 barriers/block).
//  - A fragments: raw fp32 X loaded as two explicit uint4 per fragment
//    (the 16B load pattern proven since r1), packed to bf16 at consume
//    time with shift/and/or only -- eliminates the X-conversion prep pass.
//  - fused row-dot epilogue via atomicAdd into rowacc; sigmoid separate.
// All register-array indices compile-time (round-6 lesson).
__global__ __launch_bounds__(256, 2) void gemm_kernel(
        const float*   __restrict__ Xf,    // [B_ROWS][F] fp32
        const ushort_t* __restrict__ Bp,   // packed A_sym chunks
        float*         __restrict__ rowacc) {
    __shared__ ushort_t Bs[2 * 16 * 512];  // 32 KB

    const int f   = blockIdx.x;          // 0..2047
    const int xcd = f & 7;
    const int s   = f >> 3;
    const int n   = s & 7;
    const int z   = (s >> 3) & 1;
    const int y   = s >> 4;              // 0..15
    const int blockM = (xcd * 16 + y) * 128;
    const int blockN = n * 128;
    const int kg0    = z * 16;           // 16 k-groups of 32

    const int tid   = threadIdx.x;
    const int lane  = tid & 63;
    const int wave  = tid >> 6;
    const int waveM = wave >> 1;
    const int waveN = wave & 1;
    const int quad  = lane >> 4;
    const int l16   = lane & 15;

    // A-fragment (mi, t), this lane: row = blockM + waveM*64 + mi*16 + l16,
    // cols = (kg0 + t)*32 + quad*8 .. +8   (verified == r9's Xp mapping)
    const float* pa = Xf + (size_t)(blockM + waveM * 64 + l16) * F + kg0 * 32 + quad * 8;

    // B staging: each wave stages 4 of 16 1KB chunks per 16KB buffer
    const int q0  = wave * 4;
    const int ngB = n * 8;

#define STAGE_B(c, buf)                                                        \
    {                                                                          \
        _Pragma("unroll")                                                      \
        for (int q = 0; q < 4; ++q) {                                          \
            const int qq  = q0 + q;                                            \
            const int kgl = qq >> 3, ngl = qq & 7;                             \
            gload_lds16(Bp + (size_t)((ngB + ngl) * 32 + kg0 + (c) * 2 + kgl) * 512 + lane * 8, \
                        Bs + (buf) * 8192 + (kgl * 8 + ngl) * 512);            \
        }                                                                      \
    }

    v4f acc[4][4];
#pragma unroll
    for (int i = 0; i < 4; i++)
#pragma unroll
        for (int j = 0; j < 4; j++) acc[i][j] = (v4f)(0.0f);

    uint4 a0l[4], a0h[4], a1l[4], a1h[4];
    v8s bfr[4];

    // prologue: stage chunk 0, prefetch A t=0
    STAGE_B(0, 0)
#pragma unroll
    for (int mi = 0; mi < 4; ++mi) {
        a0l[mi] = *(const uint4*)(pa + (size_t)mi * 16 * F);
        a0h[mi] = *(const uint4*)(pa + (size_t)mi * 16 * F + 4);
    }
    __syncthreads();  // chunk 0 staged

#pragma unroll
    for (int c = 0; c < 8; ++c) {
        const int buf = c & 1;
        if (c < 7) STAGE_B(c + 1, 1 - buf)  // in flight across this chunk

        // ---- t = 2c (even kg of chunk) ----
#pragma unroll
        for (int ni = 0; ni < 4; ++ni)
            bfr[ni] = *(const v8s*)(Bs + buf * 8192 + (0 * 8 + waveN * 4 + ni) * 512 + lane * 8);
#pragma unroll
        for (int mi = 0; mi < 4; ++mi) {
            a1l[mi] = *(const uint4*)(pa + (size_t)mi * 16 * F + (2 * c + 1) * 32);
            a1h[mi] = *(const uint4*)(pa + (size_t)mi * 16 * F + (2 * c + 1) * 32 + 4);
        }
#pragma unroll
        for (int mi = 0; mi < 4; ++mi) {
            const v8s af = pack_frag(a0l[mi], a0h[mi]);
#pragma unroll
            for (int ni = 0; ni < 4; ++ni)
                acc[mi][ni] = __builtin_amdgcn_mfma_f32_16x16x32_bf16(
                    af, bfr[ni], acc[mi][ni], 0, 0, 0);
        }

        // ---- t = 2c+1 (odd kg of chunk) ----
#pragma unroll
        for (int ni = 0; ni < 4; ++ni)
            bfr[ni] = *(const v8s*)(Bs + buf * 8192 + (1 * 8 + waveN * 4 + ni) * 512 + lane * 8);
        if (c < 7) {
#pragma unroll
            for (int mi = 0; mi < 4; ++mi) {
                a0l[mi] = *(const uint4*)(pa + (size_t)mi * 16 * F + (2 * c + 2) * 32);
                a0h[mi] = *(const uint4*)(pa + (size_t)mi * 16 * F + (2 * c + 2) * 32 + 4);
            }
        }
#pragma unroll
        for (int mi = 0; mi < 4; ++mi) {
            const v8s af = pack_frag(a1l[mi], a1h[mi]);
#pragma unroll
            for (int ni = 0; ni < 4; ++ni)
                acc[mi][ni] = __builtin_amdgcn_mfma_f32_16x16x32_bf16(
                    af, bfr[ni], acc[mi][ni], 0, 0, 0);
        }

        if (c < 7) __syncthreads();  // gates buffer reuse; staging c+1 landed
    }
#undef STAGE_B

    // Epilogue: C/D mapping (verified): col = lane&15, row = quad*4 + reg.
#pragma unroll
    for (int mi = 0; mi < 4; mi++) {
#pragma unroll
        for (int r = 0; r < 4; r++) {
            const int b = blockM + waveM * 64 + mi * 16 + quad * 4 + r;
            const float* xr = Xf + (size_t)b * F + blockN + waveN * 64 + l16;
            float pv = acc[mi][0][r] * xr[0]
                     + acc[mi][1][r] * xr[16]
                     + acc[mi][2][r] * xr[32]
                     + acc[mi][3][r] * xr[48];
            pv += __shfl_xor(pv, 1);
            pv += __shfl_xor(pv, 2);
            pv += __shfl_xor(pv, 4);
            pv += __shfl_xor(pv, 8);
            if (l16 == 0) atomicAdd(&rowacc[b], pv);
        }
    }
}

__global__ void sigmoid_kernel(const float* __restrict__ acc, float* __restrict__ out) {
    int b = blockIdx.x * blockDim.x + threadIdx.x;
    out[b] = 1.0f / (1.0f + __expf(-acc[b]));
}

// Correctness fallback if workspace is too small: direct per-row computation.
__global__ void fallback_kernel(const float* __restrict__ x, const float* __restrict__ w,
                                float* __restrict__ out) {
    __shared__ float xs[F];
    __shared__ float partial[4];
    const int b = blockIdx.x;
    for (int i = threadIdx.x; i < F; i += 256) xs[i] = x[(size_t)b * F + i];
    __syncthreads();
    float s = 0.0f;
    for (int i = threadIdx.x; i < F - 1; i += 256) {
        const float xi = xs[i];
        const int kbase = i * (F - 1) - (i * (i - 1)) / 2 - i - 1;
        for (int j = i + 1; j < F; j++) s += w[kbase + j] * xi * xs[j];
    }
    for (int off = 32; off; off >>= 1) s += __shfl_down(s, off);
    if ((threadIdx.x & 63) == 0) partial[threadIdx.x >> 6] = s;
    __syncthreads();
    if (threadIdx.x == 0) {
        float t = partial[0] + partial[1] + partial[2] + partial[3];
        out[b] = 1.0f / (1.0f + __expf(-t));
    }
}

extern "C" void kernel_launch(void* const* d_in, const int* in_sizes, int n_in,
                              void* d_out, int out_size, void* d_ws, size_t ws_size,
                              hipStream_t stream) {
    const float* x = (const float*)d_in[0];
    const float* w = (const float*)d_in[1];
    float* out = (float*)d_out;

    const size_t acc_bytes = 65536;                 // 16384 fp32
    const size_t B_bytes   = (size_t)F * F * 2;     // 2 MiB packed A_sym
    const size_t needed = acc_bytes + B_bytes;

    if (ws_size < needed) {
        fallback_kernel<<<B_ROWS, 256, 0, stream>>>(x, w, out);
        return;
    }

    float*    acc = (float*)d_ws;
    ushort_t* Bp  = (ushort_t*)((char*)d_ws + acc_bytes);

    // prep: 64 (acc zero) + 512 (pack B)
    prep_kernel<<<576, 256, 0, stream>>>(w, Bp, acc);
    gemm_kernel<<<2048, 256, 0, stream>>>(x, Bp, acc);
    sigmoid_kernel<<<B_ROWS / 256, 256, 0, stream>>>(acc, out);
}